// Round 15
// baseline (294.175 us; speedup 1.0000x reference)
//
#include <hip/hip_runtime.h>

constexpr int N = 100000;
constexpr int E = 1600000;
constexpr int NB = (N + 511) / 512;     // 196 dst-buckets of 512 nodes
constexpr int CAPB = 9216;              // fixed bucket capacity (mean 8168, +11 sigma)

using bf16x8 = __attribute__((ext_vector_type(8))) short;
using f32x4  = __attribute__((ext_vector_type(4))) float;

__device__ inline unsigned short f2bf(float x) {
    unsigned int b = __builtin_bit_cast(unsigned int, x);
    b = (b + 0x7FFFu + ((b >> 16) & 1u)) >> 16;
    return (unsigned short)b;
}
__device__ inline float bf2f(unsigned int u) {
    unsigned int b = u << 16;
    return __builtin_bit_cast(float, b);
}

// ================= unified fp32->bf16 prep (weights + x) + bcur init =================
struct WC13 {
    const float* s[13];
    unsigned short* d[13];
    int n8[13];     // element count / 8
};
__global__ __launch_bounds__(256) void conv_all(WC13 wc, int* __restrict__ bcur) {
    const int mi = blockIdx.y;
    if (mi == 0 && blockIdx.x == 0 && threadIdx.x < NB)
        bcur[threadIdx.x] = threadIdx.x * CAPB;   // binit folded
    const float* s = wc.s[mi];
    unsigned short* d = wc.d[mi];
    const int n8 = wc.n8[mi];
    for (int i = blockIdx.x * 256 + threadIdx.x; i < n8; i += gridDim.x * 256) {
        const float* p = s + (size_t)i * 8;
        float4 v0 = *(const float4*)p;
        float4 v1 = *(const float4*)(p + 4);
        uint4 o;
        o.x = (unsigned)f2bf(v0.x) | ((unsigned)f2bf(v0.y) << 16);
        o.y = (unsigned)f2bf(v0.z) | ((unsigned)f2bf(v0.w) << 16);
        o.z = (unsigned)f2bf(v1.x) | ((unsigned)f2bf(v1.y) << 16);
        o.w = (unsigned)f2bf(v1.z) | ((unsigned)f2bf(v1.w) << 16);
        *(uint4*)(d + (size_t)i * 8) = o;
    }
}

// ================= bucketed CSR build (fixed-capacity, R13/R14-verified) =================
__global__ __launch_bounds__(1024) void bucket_scatter(const int* __restrict__ ei,
                                                       int* __restrict__ bcur,
                                                       int* __restrict__ pairs) {
    __shared__ int lh[NB], lbase[NB], lcur[NB];
    const int per = (E + gridDim.x - 1) / gridDim.x;
    const int beg = blockIdx.x * per;
    const int end = min(E, beg + per);
    for (int i = threadIdx.x; i < NB; i += 1024) { lh[i] = 0; lcur[i] = 0; }
    __syncthreads();
    for (int e = beg + threadIdx.x; e < end; e += 1024)
        atomicAdd(&lh[ei[E + e] >> 9], 1);
    __syncthreads();
    for (int i = threadIdx.x; i < NB; i += 1024)
        lbase[i] = lh[i] ? atomicAdd(&bcur[i], lh[i]) : 0;
    __syncthreads();
    for (int e = beg + threadIdx.x; e < end; e += 1024) {
        int s = ei[e], d = ei[E + e];
        int b = d >> 9;
        int r = atomicAdd(&lcur[b], 1);
        int p = lbase[b] + r;
        if (p < (b + 1) * CAPB) pairs[p] = (s << 9) | (d & 511);  // overflow guard
    }
}

__global__ __launch_bounds__(256) void bucket_csr(const int* __restrict__ pairs,
                                                  const int* __restrict__ bcur,
                                                  int* __restrict__ csr,
                                                  int* __restrict__ off,
                                                  int* __restrict__ endo) {
    __shared__ int lcsr[CAPB];
    __shared__ int lh[512], lo[512], lc[512], st[256];
    const int b = blockIdx.x;
    const int base = b * CAPB;
    int cnt = bcur[b] - base;
    if (cnt > CAPB) cnt = CAPB;
    const int t = threadIdx.x;
    lh[t] = 0; lh[t + 256] = 0;
    __syncthreads();
    for (int i = t; i < cnt; i += 256)
        atomicAdd(&lh[pairs[base + i] & 511], 1);
    __syncthreads();
    int a0 = lh[2 * t], a1 = lh[2 * t + 1];
    int ps = a0 + a1;
    st[t] = ps;
    __syncthreads();
    for (int d = 1; d < 256; d <<= 1) {
        int u = (t >= d) ? st[t - d] : 0;
        __syncthreads();
        st[t] += u;
        __syncthreads();
    }
    int excl = st[t] - ps;
    lo[2 * t] = excl;      lo[2 * t + 1] = excl + a0;
    lc[2 * t] = excl;      lc[2 * t + 1] = excl + a0;
    __syncthreads();
    {
        int node0 = b * 512 + 2 * t;
        if (node0 < N)     { off[node0] = base + excl;          endo[node0] = base + excl + a0; }
        int node1 = node0 + 1;
        if (node1 < N)     { off[node1] = base + excl + a0;     endo[node1] = base + excl + a0 + a1; }
    }
    for (int i = t; i < cnt; i += 256) {
        int v = pairs[base + i];
        int pos = atomicAdd(&lc[v & 511], 1);
        if (pos < CAPB) lcsr[pos] = v >> 9;
    }
    __syncthreads();
    for (int i = t; i < cnt; i += 256) csr[base + i] = lcsr[i];
}

// ================= pull aggregation over bf16 messages =================
// MODE 0: write bf16 agg only. MODE 1: fp32 add into outf. MODE 2: both.
// Degree-split x4 (R14: split-2 still latency-bound): 4 sub-groups gather
// quarter-lists (4x unrolled), merged via 2 __shfl_xor steps.
template<int C, int MODE>
__global__ __launch_bounds__(256) void pull_bf(const unsigned short* __restrict__ feat,
                                               const int* __restrict__ off,
                                               const int* __restrict__ endo,
                                               const int* __restrict__ csr,
                                               float* __restrict__ outf,
                                               unsigned short* __restrict__ outb) {
    constexpr int TPN = C / 8;          // threads per node per sub-group
    int t = blockIdx.x * 256 + threadIdx.x;
    int n = t / (4 * TPN);
    int r = t % (4 * TPN);
    int sub = r / TPN;
    int g = r % TPN;
    if (n >= N) return;
    int beg = off[n];
    int cnt = endo[n] - beg;
    int q = cnt >> 2, rem = cnt & 3;
    int j    = beg + sub * q + min(sub, rem);
    int jend = j + q + (sub < rem ? 1 : 0);

    float a[8];
    #pragma unroll
    for (int i = 0; i < 8; ++i) a[i] = 0.f;

    for (; j + 4 <= jend; j += 4) {
        int s0 = csr[j], s1 = csr[j + 1], s2 = csr[j + 2], s3 = csr[j + 3];
        uint4 v0 = *(const uint4*)(feat + (size_t)s0 * C + g * 8);
        uint4 v1 = *(const uint4*)(feat + (size_t)s1 * C + g * 8);
        uint4 v2 = *(const uint4*)(feat + (size_t)s2 * C + g * 8);
        uint4 v3 = *(const uint4*)(feat + (size_t)s3 * C + g * 8);
        a[0] += bf2f(v0.x & 0xFFFFu) + bf2f(v1.x & 0xFFFFu) + bf2f(v2.x & 0xFFFFu) + bf2f(v3.x & 0xFFFFu);
        a[1] += bf2f(v0.x >> 16)     + bf2f(v1.x >> 16)     + bf2f(v2.x >> 16)     + bf2f(v3.x >> 16);
        a[2] += bf2f(v0.y & 0xFFFFu) + bf2f(v1.y & 0xFFFFu) + bf2f(v2.y & 0xFFFFu) + bf2f(v3.y & 0xFFFFu);
        a[3] += bf2f(v0.y >> 16)     + bf2f(v1.y >> 16)     + bf2f(v2.y >> 16)     + bf2f(v3.y >> 16);
        a[4] += bf2f(v0.z & 0xFFFFu) + bf2f(v1.z & 0xFFFFu) + bf2f(v2.z & 0xFFFFu) + bf2f(v3.z & 0xFFFFu);
        a[5] += bf2f(v0.z >> 16)     + bf2f(v1.z >> 16)     + bf2f(v2.z >> 16)     + bf2f(v3.z >> 16);
        a[6] += bf2f(v0.w & 0xFFFFu) + bf2f(v1.w & 0xFFFFu) + bf2f(v2.w & 0xFFFFu) + bf2f(v3.w & 0xFFFFu);
        a[7] += bf2f(v0.w >> 16)     + bf2f(v1.w >> 16)     + bf2f(v2.w >> 16)     + bf2f(v3.w >> 16);
    }
    for (; j < jend; ++j) {
        int s = csr[j];
        uint4 v = *(const uint4*)(feat + (size_t)s * C + g * 8);
        a[0] += bf2f(v.x & 0xFFFFu); a[1] += bf2f(v.x >> 16);
        a[2] += bf2f(v.y & 0xFFFFu); a[3] += bf2f(v.y >> 16);
        a[4] += bf2f(v.z & 0xFFFFu); a[5] += bf2f(v.z >> 16);
        a[6] += bf2f(v.w & 0xFFFFu); a[7] += bf2f(v.w >> 16);
    }
    // merge 4 sub-groups (lane deltas TPN, 2*TPN -- stays within 32-lane group)
    #pragma unroll
    for (int i = 0; i < 8; ++i) a[i] += __shfl_xor(a[i], TPN);
    #pragma unroll
    for (int i = 0; i < 8; ++i) a[i] += __shfl_xor(a[i], 2 * TPN);
    if (sub) return;

    if (MODE >= 1) {
        float* op = outf + (size_t)n * C + g * 8;
        float4 b0 = *(const float4*)op, b1 = *(const float4*)(op + 4);
        a[0] += b0.x; a[1] += b0.y; a[2] += b0.z; a[3] += b0.w;
        a[4] += b1.x; a[5] += b1.y; a[6] += b1.z; a[7] += b1.w;
        *(float4*)op       = make_float4(a[0], a[1], a[2], a[3]);
        *(float4*)(op + 4) = make_float4(a[4], a[5], a[6], a[7]);
    }
    if (MODE != 1) {
        uint4 o;
        o.x = (unsigned)f2bf(a[0]) | ((unsigned)f2bf(a[1]) << 16);
        o.y = (unsigned)f2bf(a[2]) | ((unsigned)f2bf(a[3]) << 16);
        o.z = (unsigned)f2bf(a[4]) | ((unsigned)f2bf(a[5]) << 16);
        o.w = (unsigned)f2bf(a[6]) | ((unsigned)f2bf(a[7]) << 16);
        *(uint4*)(outb + (size_t)n * C + g * 8) = o;
    }
}

// ================= MFMA bf16 GEMM (R8-verified) =================
template<int K1, int K2, int M, bool RELU, bool OBF>
__global__ __launch_bounds__(256) void gemm_mfma(
    const unsigned short* __restrict__ in1, const unsigned short* __restrict__ W1,
    const unsigned short* __restrict__ in2, const unsigned short* __restrict__ W2,
    const float* __restrict__ bias, void* __restrict__ outv)
{
    constexpr int KV = K1 + K2;
    constexpr int SK = KV + 8;
    constexpr int NF = M / 16;
    __shared__ unsigned short As[64 * SK];
    __shared__ unsigned short Bs[M * SK];

    const int tid = threadIdx.x;
    const int row0 = blockIdx.x * 64;

    constexpr int AV = 64 * (KV / 8);
    for (int idx = tid; idx < AV; idx += 256) {
        int r = idx / (KV / 8), c = (idx % (KV / 8)) * 8;
        int rr = row0 + r;
        uint4 v = {0u, 0u, 0u, 0u};
        if (rr < N) {
            if constexpr (K2 == 0) {
                v = *(const uint4*)(in1 + (size_t)rr * K1 + c);
            } else {
                v = (c < K1) ? *(const uint4*)(in1 + (size_t)rr * K1 + c)
                             : *(const uint4*)(in2 + (size_t)rr * K2 + (c - K1));
            }
        }
        *(uint4*)&As[r * SK + c] = v;
    }
    constexpr int BV = M * (KV / 8);
    for (int idx = tid; idx < BV; idx += 256) {
        int m = idx / (KV / 8), c = (idx % (KV / 8)) * 8;
        uint4 v;
        if constexpr (K2 == 0) {
            v = *(const uint4*)(W1 + (size_t)m * K1 + c);
        } else {
            v = (c < K1) ? *(const uint4*)(W1 + (size_t)m * K1 + c)
                         : *(const uint4*)(W2 + (size_t)m * K2 + (c - K1));
        }
        *(uint4*)&Bs[m * SK + c] = v;
    }
    __syncthreads();

    const int lane = tid & 63;
    const int wv   = tid >> 6;
    const int lrow = lane & 15;
    const int kg   = lane >> 4;

    f32x4 acc[NF];
    #pragma unroll
    for (int cf = 0; cf < NF; ++cf) acc[cf] = (f32x4){0.f, 0.f, 0.f, 0.f};

    #pragma unroll
    for (int k0 = 0; k0 < KV; k0 += 32) {
        bf16x8 a = *(const bf16x8*)&As[(wv * 16 + lrow) * SK + k0 + kg * 8];
        #pragma unroll
        for (int cf = 0; cf < NF; ++cf) {
            bf16x8 b = *(const bf16x8*)&Bs[(cf * 16 + lrow) * SK + k0 + kg * 8];
            acc[cf] = __builtin_amdgcn_mfma_f32_16x16x32_bf16(a, b, acc[cf], 0, 0, 0);
        }
    }

    #pragma unroll
    for (int cf = 0; cf < NF; ++cf) {
        int col = cf * 16 + lrow;
        float bsv = bias ? bias[col] : 0.f;
        #pragma unroll
        for (int r = 0; r < 4; ++r) {
            int row = row0 + wv * 16 + kg * 4 + r;
            if (row < N) {
                float v = acc[cf][r] + bsv;
                if (RELU) v = fmaxf(v, 0.f);
                if constexpr (OBF)
                    ((unsigned short*)outv)[(size_t)row * M + col] = f2bf(v);
                else
                    ((float*)outv)[(size_t)row * M + col] = v;
            }
        }
    }
}

// ================= fused proj+msg+root GEMM (conv2/conv4 head, R11-verified) =================
template<int M2>
__global__ __launch_bounds__(256) void gemm_proj3(
    const unsigned short* __restrict__ in, const unsigned short* __restrict__ Wp,
    const float* __restrict__ bp,
    const unsigned short* __restrict__ Wl, const unsigned short* __restrict__ Wr,
    const float* __restrict__ bl,
    unsigned short* __restrict__ msg, float* __restrict__ zout)
{
    constexpr int K = 128, SK = K + 8, NF = 8, NF2 = M2 / 16;
    __shared__ unsigned short As[64 * SK];
    __shared__ unsigned short Bs[128 * SK];
    __shared__ unsigned short Hs[64 * SK];
    const int tid = threadIdx.x;
    const int row0 = blockIdx.x * 64;

    for (int idx = tid; idx < 64 * 16; idx += 256) {
        int r = idx >> 4, c = (idx & 15) * 8;
        int n = row0 + r;
        uint4 v = {0u, 0u, 0u, 0u};
        if (n < N) v = *(const uint4*)(in + (size_t)n * K + c);
        *(uint4*)&As[r * SK + c] = v;
    }
    for (int idx = tid; idx < 128 * 16; idx += 256) {
        int m = idx >> 4, c = (idx & 15) * 8;
        *(uint4*)&Bs[m * SK + c] = *(const uint4*)(Wp + (size_t)m * K + c);
    }
    __syncthreads();

    const int lane = tid & 63;
    const int wv = tid >> 6, lrow = lane & 15, kg = lane >> 4;

    f32x4 acc[NF];
    #pragma unroll
    for (int cf = 0; cf < NF; ++cf) acc[cf] = (f32x4){0.f, 0.f, 0.f, 0.f};
    #pragma unroll
    for (int k0 = 0; k0 < K; k0 += 32) {
        bf16x8 a = *(const bf16x8*)&As[(wv * 16 + lrow) * SK + k0 + kg * 8];
        #pragma unroll
        for (int cf = 0; cf < NF; ++cf) {
            bf16x8 b = *(const bf16x8*)&Bs[(cf * 16 + lrow) * SK + k0 + kg * 8];
            acc[cf] = __builtin_amdgcn_mfma_f32_16x16x32_bf16(a, b, acc[cf], 0, 0, 0);
        }
    }
    #pragma unroll
    for (int cf = 0; cf < NF; ++cf) {
        int col = cf * 16 + lrow;
        float bv = bp[col];
        #pragma unroll
        for (int r = 0; r < 4; ++r)
            Hs[(wv * 16 + kg * 4 + r) * SK + col] = f2bf(fmaxf(acc[cf][r] + bv, 0.f));
    }
    __syncthreads();
    for (int idx = tid; idx < 2 * M2 * 16; idx += 256) {
        int m = idx >> 4, c = (idx & 15) * 8;
        uint4 v = (m < M2) ? *(const uint4*)(Wl + (size_t)m * K + c)
                           : *(const uint4*)(Wr + (size_t)(m - M2) * K + c);
        *(uint4*)&Bs[m * SK + c] = v;
    }
    __syncthreads();

    f32x4 am[NF2], az[NF2];
    #pragma unroll
    for (int cf = 0; cf < NF2; ++cf) {
        am[cf] = (f32x4){0.f, 0.f, 0.f, 0.f};
        az[cf] = (f32x4){0.f, 0.f, 0.f, 0.f};
    }
    #pragma unroll
    for (int k0 = 0; k0 < K; k0 += 32) {
        bf16x8 aH = *(const bf16x8*)&Hs[(wv * 16 + lrow) * SK + k0 + kg * 8];
        bf16x8 aR = *(const bf16x8*)&As[(wv * 16 + lrow) * SK + k0 + kg * 8];
        #pragma unroll
        for (int cf = 0; cf < NF2; ++cf) {
            bf16x8 b1 = *(const bf16x8*)&Bs[(cf * 16 + lrow) * SK + k0 + kg * 8];
            bf16x8 b2 = *(const bf16x8*)&Bs[(M2 + cf * 16 + lrow) * SK + k0 + kg * 8];
            am[cf] = __builtin_amdgcn_mfma_f32_16x16x32_bf16(aH, b1, am[cf], 0, 0, 0);
            az[cf] = __builtin_amdgcn_mfma_f32_16x16x32_bf16(aR, b2, az[cf], 0, 0, 0);
        }
    }
    #pragma unroll
    for (int cf = 0; cf < NF2; ++cf) {
        int col = cf * 16 + lrow;
        float blv = bl[col];
        #pragma unroll
        for (int r = 0; r < 4; ++r) {
            int row = row0 + wv * 16 + kg * 4 + r;
            if (row < N) {
                msg[(size_t)row * M2 + col]  = f2bf(am[cf][r]);
                zout[(size_t)row * M2 + col] = az[cf][r] + blv;
            }
        }
    }
}

extern "C" void kernel_launch(void* const* d_in, const int* in_sizes, int n_in,
                              void* d_out, int out_size, void* d_ws, size_t ws_size,
                              hipStream_t stream)
{
    const float* x   = (const float*)d_in[0];
    const int*   ei  = (const int*)d_in[1];
    const float *e1_Wp=(const float*)d_in[2],  *e1_bp=(const float*)d_in[3],
                *e1_Wl=(const float*)d_in[4],  *e1_bl=(const float*)d_in[5],
                *e1_Wr=(const float*)d_in[6];
    const float *e2_Wp=(const float*)d_in[7],  *e2_bp=(const float*)d_in[8],
                *e2_Wl=(const float*)d_in[9],  *e2_bl=(const float*)d_in[10],
                *e2_Wr=(const float*)d_in[11];
    const float *d1_Wp=(const float*)d_in[12], *d1_bp=(const float*)d_in[13],
                *d1_Wl=(const float*)d_in[14], *d1_bl=(const float*)d_in[15],
                *d1_Wr=(const float*)d_in[16];
    const float *d2_Wp=(const float*)d_in[17], *d2_bp=(const float*)d_in[18],
                *d2_Wl=(const float*)d_in[19], *d2_bl=(const float*)d_in[20],
                *d2_Wr=(const float*)d_in[21];

    typedef unsigned short u16;

    // ---- workspace ----
    int* off  = (int*)d_ws;                       // N
    int* endo = off + N;                          // N
    int* csr  = endo + N;                         // NB*CAPB (bucket-strided)
    u16* xbf  = (u16*)(csr + NB * CAPB);          // [N][64]
    u16* R1bf = xbf  + (size_t)N * 64;            // [N][128]
    u16* MSG  = R1bf + (size_t)N * 128;           // [N][64] msgs
    u16* AGG  = MSG  + (size_t)N * 64;            // [N][64] aggregates
    u16* zbf  = AGG  + (size_t)N * 64;            // [N][32]
    u16* WB   = zbf  + (size_t)N * 32;            // bf16 weights
    int* bcur = (int*)(WB + 87040);               // NB
    int* pairs = (int*)MSG;   // NB*CAPB ints; CSR build precedes MSG use

    u16* b_e1Wp = WB;
    u16* b_e1Wl = b_e1Wp + 4096;
    u16* b_e1Wr = b_e1Wl + 8192;
    u16* b_e2Wr = b_e1Wr + 8192;
    u16* b_e2Wp = b_e2Wr + 4096;
    u16* b_e2Wl = b_e2Wp + 16384;
    u16* b_d1Wp = b_e2Wl + 4096;
    u16* b_d1Wl = b_d1Wp + 1024;
    u16* b_d1Wr = b_d1Wl + 4096;
    u16* b_d2Wr = b_d1Wr + 4096;
    u16* b_d2Wp = b_d2Wr + 8192;
    u16* b_d2Wl = b_d2Wp + 16384;

    float* xrec = (float*)d_out;                  // [N][64]
    float* z    = xrec + (size_t)N * 64;          // [N][32]

    const int GM = (N + 63) / 64;                 // 1563

    // ---- unified prep: 12 weight converts + x convert + bcur init ----
    WC13 wc;
    const float* ws_[13] = {e1_Wp, e1_Wl, e1_Wr, e2_Wr, e2_Wp, e2_Wl,
                            d1_Wp, d1_Wl, d1_Wr, d2_Wr, d2_Wp, d2_Wl, x};
    u16* wd_[13] = {b_e1Wp, b_e1Wl, b_e1Wr, b_e2Wr, b_e2Wp, b_e2Wl,
                    b_d1Wp, b_d1Wl, b_d1Wr, b_d2Wr, b_d2Wp, b_d2Wl, xbf};
    int wn_[13] = {512, 1024, 1024, 512, 2048, 512,
                   128, 512, 512, 1024, 2048, 1024, N * 8};
    for (int i = 0; i < 13; ++i) { wc.s[i] = ws_[i]; wc.d[i] = wd_[i]; wc.n8[i] = wn_[i]; }
    conv_all<<<dim3(128, 13), 256, 0, stream>>>(wc, bcur);

    // ---- bucketed CSR build ----
    bucket_scatter<<<256, 1024, 0, stream>>>(ei, bcur, pairs);
    bucket_csr<<<NB, 256, 0, stream>>>(pairs, bcur, csr, off, endo);

    // ---- conv1 (e1): 64 -> 128, relu ----
    gemm_mfma<64,0,64,true,true><<<GM, 256, 0, stream>>>(xbf, b_e1Wp, nullptr, nullptr, e1_bp, MSG);
    pull_bf<64,0><<<(N*32 + 255)/256, 256, 0, stream>>>(MSG, off, endo, csr, nullptr, AGG);
    gemm_mfma<64,64,128,true,true><<<GM, 256, 0, stream>>>(AGG, b_e1Wl, xbf, b_e1Wr, e1_bl, R1bf);

    // ---- conv2 (e2): 128 -> 32 = z ----
    gemm_proj3<32><<<GM, 256, 0, stream>>>(R1bf, b_e2Wp, e2_bp, b_e2Wl, b_e2Wr, e2_bl, MSG, z);
    pull_bf<32,2><<<(N*16 + 255)/256, 256, 0, stream>>>(MSG, off, endo, csr, z, zbf);

    // ---- conv3 (d1): 32 -> 128, relu ----
    gemm_mfma<32,0,32,true,true><<<GM, 256, 0, stream>>>(zbf, b_d1Wp, nullptr, nullptr, d1_bp, MSG);
    pull_bf<32,0><<<(N*16 + 255)/256, 256, 0, stream>>>(MSG, off, endo, csr, nullptr, AGG);
    gemm_mfma<32,32,128,true,true><<<GM, 256, 0, stream>>>(AGG, b_d1Wl, zbf, b_d1Wr, d1_bl, R1bf);

    // ---- conv4 (d2): 128 -> 64 = x_rec ----
    gemm_proj3<64><<<GM, 256, 0, stream>>>(R1bf, b_d2Wp, d2_bp, b_d2Wl, b_d2Wr, d2_bl, MSG, xrec);
    pull_bf<64,1><<<(N*32 + 255)/256, 256, 0, stream>>>(MSG, off, endo, csr, xrec, nullptr);
}

// Round 16
// 284.567 us; speedup vs baseline: 1.0338x; 1.0338x over previous
//
#include <hip/hip_runtime.h>

constexpr int N = 100000;
constexpr int E = 1600000;
constexpr int NB = (N + 511) / 512;     // 196 dst-buckets of 512 nodes
constexpr int CAPB = 9216;              // fixed bucket capacity (mean 8168, +11 sigma)

using bf16x8 = __attribute__((ext_vector_type(8))) short;
using f32x4  = __attribute__((ext_vector_type(4))) float;

__device__ inline unsigned short f2bf(float x) {
    unsigned int b = __builtin_bit_cast(unsigned int, x);
    b = (b + 0x7FFFu + ((b >> 16) & 1u)) >> 16;
    return (unsigned short)b;
}
__device__ inline float bf2f(unsigned int u) {
    unsigned int b = u << 16;
    return __builtin_bit_cast(float, b);
}

// ================= unified fp32->bf16 prep (weights + x) + bcur init =================
struct WC13 {
    const float* s[13];
    unsigned short* d[13];
    int n8[13];     // element count / 8
};
__global__ __launch_bounds__(256) void conv_all(WC13 wc, int* __restrict__ bcur) {
    const int mi = blockIdx.y;
    if (mi == 0 && blockIdx.x == 0 && threadIdx.x < NB)
        bcur[threadIdx.x] = threadIdx.x * CAPB;   // binit folded
    const float* s = wc.s[mi];
    unsigned short* d = wc.d[mi];
    const int n8 = wc.n8[mi];
    for (int i = blockIdx.x * 256 + threadIdx.x; i < n8; i += gridDim.x * 256) {
        const float* p = s + (size_t)i * 8;
        float4 v0 = *(const float4*)p;
        float4 v1 = *(const float4*)(p + 4);
        uint4 o;
        o.x = (unsigned)f2bf(v0.x) | ((unsigned)f2bf(v0.y) << 16);
        o.y = (unsigned)f2bf(v0.z) | ((unsigned)f2bf(v0.w) << 16);
        o.z = (unsigned)f2bf(v1.x) | ((unsigned)f2bf(v1.y) << 16);
        o.w = (unsigned)f2bf(v1.z) | ((unsigned)f2bf(v1.w) << 16);
        *(uint4*)(d + (size_t)i * 8) = o;
    }
}

// ================= bucketed CSR build (fixed-capacity, R13/R14-verified) =================
__global__ __launch_bounds__(1024) void bucket_scatter(const int* __restrict__ ei,
                                                       int* __restrict__ bcur,
                                                       int* __restrict__ pairs) {
    __shared__ int lh[NB], lbase[NB], lcur[NB];
    const int per = (E + gridDim.x - 1) / gridDim.x;
    const int beg = blockIdx.x * per;
    const int end = min(E, beg + per);
    for (int i = threadIdx.x; i < NB; i += 1024) { lh[i] = 0; lcur[i] = 0; }
    __syncthreads();
    for (int e = beg + threadIdx.x; e < end; e += 1024)
        atomicAdd(&lh[ei[E + e] >> 9], 1);
    __syncthreads();
    for (int i = threadIdx.x; i < NB; i += 1024)
        lbase[i] = lh[i] ? atomicAdd(&bcur[i], lh[i]) : 0;
    __syncthreads();
    for (int e = beg + threadIdx.x; e < end; e += 1024) {
        int s = ei[e], d = ei[E + e];
        int b = d >> 9;
        int r = atomicAdd(&lcur[b], 1);
        int p = lbase[b] + r;
        if (p < (b + 1) * CAPB) pairs[p] = (s << 9) | (d & 511);  // overflow guard
    }
}

__global__ __launch_bounds__(256) void bucket_csr(const int* __restrict__ pairs,
                                                  const int* __restrict__ bcur,
                                                  int* __restrict__ csr,
                                                  int* __restrict__ off,
                                                  int* __restrict__ endo) {
    __shared__ int lcsr[CAPB];
    __shared__ int lh[512], lo[512], lc[512], st[256];
    const int b = blockIdx.x;
    const int base = b * CAPB;
    int cnt = bcur[b] - base;
    if (cnt > CAPB) cnt = CAPB;
    const int t = threadIdx.x;
    lh[t] = 0; lh[t + 256] = 0;
    __syncthreads();
    for (int i = t; i < cnt; i += 256)
        atomicAdd(&lh[pairs[base + i] & 511], 1);
    __syncthreads();
    int a0 = lh[2 * t], a1 = lh[2 * t + 1];
    int ps = a0 + a1;
    st[t] = ps;
    __syncthreads();
    for (int d = 1; d < 256; d <<= 1) {
        int u = (t >= d) ? st[t - d] : 0;
        __syncthreads();
        st[t] += u;
        __syncthreads();
    }
    int excl = st[t] - ps;
    lo[2 * t] = excl;      lo[2 * t + 1] = excl + a0;
    lc[2 * t] = excl;      lc[2 * t + 1] = excl + a0;
    __syncthreads();
    {
        int node0 = b * 512 + 2 * t;
        if (node0 < N)     { off[node0] = base + excl;          endo[node0] = base + excl + a0; }
        int node1 = node0 + 1;
        if (node1 < N)     { off[node1] = base + excl + a0;     endo[node1] = base + excl + a0 + a1; }
    }
    for (int i = t; i < cnt; i += 256) {
        int v = pairs[base + i];
        int pos = atomicAdd(&lc[v & 511], 1);
        if (pos < CAPB) lcsr[pos] = v >> 9;
    }
    __syncthreads();
    for (int i = t; i < cnt; i += 256) csr[base + i] = lcsr[i];
}

// ================= pull aggregation over bf16 messages =================
// MODE 0: write bf16 agg only. MODE 1: fp32 add into outf. MODE 2: both.
// Degree-split x2 (R14-verified sweet spot; R15's x4 regressed -- quarter
// lists too short for the unroll window). One __shfl_xor merge.
template<int C, int MODE>
__global__ __launch_bounds__(256) void pull_bf(const unsigned short* __restrict__ feat,
                                               const int* __restrict__ off,
                                               const int* __restrict__ endo,
                                               const int* __restrict__ csr,
                                               float* __restrict__ outf,
                                               unsigned short* __restrict__ outb) {
    constexpr int TPN = C / 8;          // threads per node per sub-group
    int t = blockIdx.x * 256 + threadIdx.x;
    int n = t / (2 * TPN);
    int r = t % (2 * TPN);
    int sub = r / TPN;
    int g = r % TPN;
    if (n >= N) return;
    int beg = off[n];
    int end = endo[n];
    int cnt = end - beg;
    int mid = beg + ((cnt + 1) >> 1);
    int j    = sub ? mid : beg;
    int jend = sub ? end : mid;

    float a[8];
    #pragma unroll
    for (int i = 0; i < 8; ++i) a[i] = 0.f;

    for (; j + 4 <= jend; j += 4) {
        int s0 = csr[j], s1 = csr[j + 1], s2 = csr[j + 2], s3 = csr[j + 3];
        uint4 v0 = *(const uint4*)(feat + (size_t)s0 * C + g * 8);
        uint4 v1 = *(const uint4*)(feat + (size_t)s1 * C + g * 8);
        uint4 v2 = *(const uint4*)(feat + (size_t)s2 * C + g * 8);
        uint4 v3 = *(const uint4*)(feat + (size_t)s3 * C + g * 8);
        a[0] += bf2f(v0.x & 0xFFFFu) + bf2f(v1.x & 0xFFFFu) + bf2f(v2.x & 0xFFFFu) + bf2f(v3.x & 0xFFFFu);
        a[1] += bf2f(v0.x >> 16)     + bf2f(v1.x >> 16)     + bf2f(v2.x >> 16)     + bf2f(v3.x >> 16);
        a[2] += bf2f(v0.y & 0xFFFFu) + bf2f(v1.y & 0xFFFFu) + bf2f(v2.y & 0xFFFFu) + bf2f(v3.y & 0xFFFFu);
        a[3] += bf2f(v0.y >> 16)     + bf2f(v1.y >> 16)     + bf2f(v2.y >> 16)     + bf2f(v3.y >> 16);
        a[4] += bf2f(v0.z & 0xFFFFu) + bf2f(v1.z & 0xFFFFu) + bf2f(v2.z & 0xFFFFu) + bf2f(v3.z & 0xFFFFu);
        a[5] += bf2f(v0.z >> 16)     + bf2f(v1.z >> 16)     + bf2f(v2.z >> 16)     + bf2f(v3.z >> 16);
        a[6] += bf2f(v0.w & 0xFFFFu) + bf2f(v1.w & 0xFFFFu) + bf2f(v2.w & 0xFFFFu) + bf2f(v3.w & 0xFFFFu);
        a[7] += bf2f(v0.w >> 16)     + bf2f(v1.w >> 16)     + bf2f(v2.w >> 16)     + bf2f(v3.w >> 16);
    }
    for (; j < jend; ++j) {
        int s = csr[j];
        uint4 v = *(const uint4*)(feat + (size_t)s * C + g * 8);
        a[0] += bf2f(v.x & 0xFFFFu); a[1] += bf2f(v.x >> 16);
        a[2] += bf2f(v.y & 0xFFFFu); a[3] += bf2f(v.y >> 16);
        a[4] += bf2f(v.z & 0xFFFFu); a[5] += bf2f(v.z >> 16);
        a[6] += bf2f(v.w & 0xFFFFu); a[7] += bf2f(v.w >> 16);
    }
    // merge the two halves (partner lane differs by TPN; same node, same g)
    #pragma unroll
    for (int i = 0; i < 8; ++i) a[i] += __shfl_xor(a[i], TPN);
    if (sub) return;

    if (MODE >= 1) {
        float* op = outf + (size_t)n * C + g * 8;
        float4 b0 = *(const float4*)op, b1 = *(const float4*)(op + 4);
        a[0] += b0.x; a[1] += b0.y; a[2] += b0.z; a[3] += b0.w;
        a[4] += b1.x; a[5] += b1.y; a[6] += b1.z; a[7] += b1.w;
        *(float4*)op       = make_float4(a[0], a[1], a[2], a[3]);
        *(float4*)(op + 4) = make_float4(a[4], a[5], a[6], a[7]);
    }
    if (MODE != 1) {
        uint4 o;
        o.x = (unsigned)f2bf(a[0]) | ((unsigned)f2bf(a[1]) << 16);
        o.y = (unsigned)f2bf(a[2]) | ((unsigned)f2bf(a[3]) << 16);
        o.z = (unsigned)f2bf(a[4]) | ((unsigned)f2bf(a[5]) << 16);
        o.w = (unsigned)f2bf(a[6]) | ((unsigned)f2bf(a[7]) << 16);
        *(uint4*)(outb + (size_t)n * C + g * 8) = o;
    }
}

// ================= MFMA bf16 GEMM (R8-verified) =================
template<int K1, int K2, int M, bool RELU, bool OBF>
__global__ __launch_bounds__(256) void gemm_mfma(
    const unsigned short* __restrict__ in1, const unsigned short* __restrict__ W1,
    const unsigned short* __restrict__ in2, const unsigned short* __restrict__ W2,
    const float* __restrict__ bias, void* __restrict__ outv)
{
    constexpr int KV = K1 + K2;
    constexpr int SK = KV + 8;
    constexpr int NF = M / 16;
    __shared__ unsigned short As[64 * SK];
    __shared__ unsigned short Bs[M * SK];

    const int tid = threadIdx.x;
    const int row0 = blockIdx.x * 64;

    constexpr int AV = 64 * (KV / 8);
    for (int idx = tid; idx < AV; idx += 256) {
        int r = idx / (KV / 8), c = (idx % (KV / 8)) * 8;
        int rr = row0 + r;
        uint4 v = {0u, 0u, 0u, 0u};
        if (rr < N) {
            if constexpr (K2 == 0) {
                v = *(const uint4*)(in1 + (size_t)rr * K1 + c);
            } else {
                v = (c < K1) ? *(const uint4*)(in1 + (size_t)rr * K1 + c)
                             : *(const uint4*)(in2 + (size_t)rr * K2 + (c - K1));
            }
        }
        *(uint4*)&As[r * SK + c] = v;
    }
    constexpr int BV = M * (KV / 8);
    for (int idx = tid; idx < BV; idx += 256) {
        int m = idx / (KV / 8), c = (idx % (KV / 8)) * 8;
        uint4 v;
        if constexpr (K2 == 0) {
            v = *(const uint4*)(W1 + (size_t)m * K1 + c);
        } else {
            v = (c < K1) ? *(const uint4*)(W1 + (size_t)m * K1 + c)
                         : *(const uint4*)(W2 + (size_t)m * K2 + (c - K1));
        }
        *(uint4*)&Bs[m * SK + c] = v;
    }
    __syncthreads();

    const int lane = tid & 63;
    const int wv   = tid >> 6;
    const int lrow = lane & 15;
    const int kg   = lane >> 4;

    f32x4 acc[NF];
    #pragma unroll
    for (int cf = 0; cf < NF; ++cf) acc[cf] = (f32x4){0.f, 0.f, 0.f, 0.f};

    #pragma unroll
    for (int k0 = 0; k0 < KV; k0 += 32) {
        bf16x8 a = *(const bf16x8*)&As[(wv * 16 + lrow) * SK + k0 + kg * 8];
        #pragma unroll
        for (int cf = 0; cf < NF; ++cf) {
            bf16x8 b = *(const bf16x8*)&Bs[(cf * 16 + lrow) * SK + k0 + kg * 8];
            acc[cf] = __builtin_amdgcn_mfma_f32_16x16x32_bf16(a, b, acc[cf], 0, 0, 0);
        }
    }

    #pragma unroll
    for (int cf = 0; cf < NF; ++cf) {
        int col = cf * 16 + lrow;
        float bsv = bias ? bias[col] : 0.f;
        #pragma unroll
        for (int r = 0; r < 4; ++r) {
            int row = row0 + wv * 16 + kg * 4 + r;
            if (row < N) {
                float v = acc[cf][r] + bsv;
                if (RELU) v = fmaxf(v, 0.f);
                if constexpr (OBF)
                    ((unsigned short*)outv)[(size_t)row * M + col] = f2bf(v);
                else
                    ((float*)outv)[(size_t)row * M + col] = v;
            }
        }
    }
}

// ================= fused proj+msg+root GEMM (conv2/conv4 head, R11-verified) =================
template<int M2>
__global__ __launch_bounds__(256) void gemm_proj3(
    const unsigned short* __restrict__ in, const unsigned short* __restrict__ Wp,
    const float* __restrict__ bp,
    const unsigned short* __restrict__ Wl, const unsigned short* __restrict__ Wr,
    const float* __restrict__ bl,
    unsigned short* __restrict__ msg, float* __restrict__ zout)
{
    constexpr int K = 128, SK = K + 8, NF = 8, NF2 = M2 / 16;
    __shared__ unsigned short As[64 * SK];
    __shared__ unsigned short Bs[128 * SK];
    __shared__ unsigned short Hs[64 * SK];
    const int tid = threadIdx.x;
    const int row0 = blockIdx.x * 64;

    for (int idx = tid; idx < 64 * 16; idx += 256) {
        int r = idx >> 4, c = (idx & 15) * 8;
        int n = row0 + r;
        uint4 v = {0u, 0u, 0u, 0u};
        if (n < N) v = *(const uint4*)(in + (size_t)n * K + c);
        *(uint4*)&As[r * SK + c] = v;
    }
    for (int idx = tid; idx < 128 * 16; idx += 256) {
        int m = idx >> 4, c = (idx & 15) * 8;
        *(uint4*)&Bs[m * SK + c] = *(const uint4*)(Wp + (size_t)m * K + c);
    }
    __syncthreads();

    const int lane = tid & 63;
    const int wv = tid >> 6, lrow = lane & 15, kg = lane >> 4;

    f32x4 acc[NF];
    #pragma unroll
    for (int cf = 0; cf < NF; ++cf) acc[cf] = (f32x4){0.f, 0.f, 0.f, 0.f};
    #pragma unroll
    for (int k0 = 0; k0 < K; k0 += 32) {
        bf16x8 a = *(const bf16x8*)&As[(wv * 16 + lrow) * SK + k0 + kg * 8];
        #pragma unroll
        for (int cf = 0; cf < NF; ++cf) {
            bf16x8 b = *(const bf16x8*)&Bs[(cf * 16 + lrow) * SK + k0 + kg * 8];
            acc[cf] = __builtin_amdgcn_mfma_f32_16x16x32_bf16(a, b, acc[cf], 0, 0, 0);
        }
    }
    #pragma unroll
    for (int cf = 0; cf < NF; ++cf) {
        int col = cf * 16 + lrow;
        float bv = bp[col];
        #pragma unroll
        for (int r = 0; r < 4; ++r)
            Hs[(wv * 16 + kg * 4 + r) * SK + col] = f2bf(fmaxf(acc[cf][r] + bv, 0.f));
    }
    __syncthreads();
    for (int idx = tid; idx < 2 * M2 * 16; idx += 256) {
        int m = idx >> 4, c = (idx & 15) * 8;
        uint4 v = (m < M2) ? *(const uint4*)(Wl + (size_t)m * K + c)
                           : *(const uint4*)(Wr + (size_t)(m - M2) * K + c);
        *(uint4*)&Bs[m * SK + c] = v;
    }
    __syncthreads();

    f32x4 am[NF2], az[NF2];
    #pragma unroll
    for (int cf = 0; cf < NF2; ++cf) {
        am[cf] = (f32x4){0.f, 0.f, 0.f, 0.f};
        az[cf] = (f32x4){0.f, 0.f, 0.f, 0.f};
    }
    #pragma unroll
    for (int k0 = 0; k0 < K; k0 += 32) {
        bf16x8 aH = *(const bf16x8*)&Hs[(wv * 16 + lrow) * SK + k0 + kg * 8];
        bf16x8 aR = *(const bf16x8*)&As[(wv * 16 + lrow) * SK + k0 + kg * 8];
        #pragma unroll
        for (int cf = 0; cf < NF2; ++cf) {
            bf16x8 b1 = *(const bf16x8*)&Bs[(cf * 16 + lrow) * SK + k0 + kg * 8];
            bf16x8 b2 = *(const bf16x8*)&Bs[(M2 + cf * 16 + lrow) * SK + k0 + kg * 8];
            am[cf] = __builtin_amdgcn_mfma_f32_16x16x32_bf16(aH, b1, am[cf], 0, 0, 0);
            az[cf] = __builtin_amdgcn_mfma_f32_16x16x32_bf16(aR, b2, az[cf], 0, 0, 0);
        }
    }
    #pragma unroll
    for (int cf = 0; cf < NF2; ++cf) {
        int col = cf * 16 + lrow;
        float blv = bl[col];
        #pragma unroll
        for (int r = 0; r < 4; ++r) {
            int row = row0 + wv * 16 + kg * 4 + r;
            if (row < N) {
                msg[(size_t)row * M2 + col]  = f2bf(am[cf][r]);
                zout[(size_t)row * M2 + col] = az[cf][r] + blv;
            }
        }
    }
}

extern "C" void kernel_launch(void* const* d_in, const int* in_sizes, int n_in,
                              void* d_out, int out_size, void* d_ws, size_t ws_size,
                              hipStream_t stream)
{
    const float* x   = (const float*)d_in[0];
    const int*   ei  = (const int*)d_in[1];
    const float *e1_Wp=(const float*)d_in[2],  *e1_bp=(const float*)d_in[3],
                *e1_Wl=(const float*)d_in[4],  *e1_bl=(const float*)d_in[5],
                *e1_Wr=(const float*)d_in[6];
    const float *e2_Wp=(const float*)d_in[7],  *e2_bp=(const float*)d_in[8],
                *e2_Wl=(const float*)d_in[9],  *e2_bl=(const float*)d_in[10],
                *e2_Wr=(const float*)d_in[11];
    const float *d1_Wp=(const float*)d_in[12], *d1_bp=(const float*)d_in[13],
                *d1_Wl=(const float*)d_in[14], *d1_bl=(const float*)d_in[15],
                *d1_Wr=(const float*)d_in[16];
    const float *d2_Wp=(const float*)d_in[17], *d2_bp=(const float*)d_in[18],
                *d2_Wl=(const float*)d_in[19], *d2_bl=(const float*)d_in[20],
                *d2_Wr=(const float*)d_in[21];

    typedef unsigned short u16;

    // ---- workspace ----
    int* off  = (int*)d_ws;                       // N
    int* endo = off + N;                          // N
    int* csr  = endo + N;                         // NB*CAPB (bucket-strided)
    u16* xbf  = (u16*)(csr + NB * CAPB);          // [N][64]
    u16* R1bf = xbf  + (size_t)N * 64;            // [N][128]
    u16* MSG  = R1bf + (size_t)N * 128;           // [N][64] msgs
    u16* AGG  = MSG  + (size_t)N * 64;            // [N][64] aggregates
    u16* zbf  = AGG  + (size_t)N * 64;            // [N][32]
    u16* WB   = zbf  + (size_t)N * 32;            // bf16 weights
    int* bcur = (int*)(WB + 87040);               // NB
    int* pairs = (int*)MSG;   // NB*CAPB ints; CSR build precedes MSG use

    u16* b_e1Wp = WB;
    u16* b_e1Wl = b_e1Wp + 4096;
    u16* b_e1Wr = b_e1Wl + 8192;
    u16* b_e2Wr = b_e1Wr + 8192;
    u16* b_e2Wp = b_e2Wr + 4096;
    u16* b_e2Wl = b_e2Wp + 16384;
    u16* b_d1Wp = b_e2Wl + 4096;
    u16* b_d1Wl = b_d1Wp + 1024;
    u16* b_d1Wr = b_d1Wl + 4096;
    u16* b_d2Wr = b_d1Wr + 4096;
    u16* b_d2Wp = b_d2Wr + 8192;
    u16* b_d2Wl = b_d2Wp + 16384;

    float* xrec = (float*)d_out;                  // [N][64]
    float* z    = xrec + (size_t)N * 64;          // [N][32]

    const int GM = (N + 63) / 64;                 // 1563

    // ---- unified prep: 12 weight converts + x convert + bcur init ----
    WC13 wc;
    const float* ws_[13] = {e1_Wp, e1_Wl, e1_Wr, e2_Wr, e2_Wp, e2_Wl,
                            d1_Wp, d1_Wl, d1_Wr, d2_Wr, d2_Wp, d2_Wl, x};
    u16* wd_[13] = {b_e1Wp, b_e1Wl, b_e1Wr, b_e2Wr, b_e2Wp, b_e2Wl,
                    b_d1Wp, b_d1Wl, b_d1Wr, b_d2Wr, b_d2Wp, b_d2Wl, xbf};
    int wn_[13] = {512, 1024, 1024, 512, 2048, 512,
                   128, 512, 512, 1024, 2048, 1024, N * 8};
    for (int i = 0; i < 13; ++i) { wc.s[i] = ws_[i]; wc.d[i] = wd_[i]; wc.n8[i] = wn_[i]; }
    conv_all<<<dim3(128, 13), 256, 0, stream>>>(wc, bcur);

    // ---- bucketed CSR build ----
    bucket_scatter<<<256, 1024, 0, stream>>>(ei, bcur, pairs);
    bucket_csr<<<NB, 256, 0, stream>>>(pairs, bcur, csr, off, endo);

    // ---- conv1 (e1): 64 -> 128, relu ----
    gemm_mfma<64,0,64,true,true><<<GM, 256, 0, stream>>>(xbf, b_e1Wp, nullptr, nullptr, e1_bp, MSG);
    pull_bf<64,0><<<(N*16 + 255)/256, 256, 0, stream>>>(MSG, off, endo, csr, nullptr, AGG);
    gemm_mfma<64,64,128,true,true><<<GM, 256, 0, stream>>>(AGG, b_e1Wl, xbf, b_e1Wr, e1_bl, R1bf);

    // ---- conv2 (e2): 128 -> 32 = z ----
    gemm_proj3<32><<<GM, 256, 0, stream>>>(R1bf, b_e2Wp, e2_bp, b_e2Wl, b_e2Wr, e2_bl, MSG, z);
    pull_bf<32,2><<<(N*8 + 255)/256, 256, 0, stream>>>(MSG, off, endo, csr, z, zbf);

    // ---- conv3 (d1): 32 -> 128, relu ----
    gemm_mfma<32,0,32,true,true><<<GM, 256, 0, stream>>>(zbf, b_d1Wp, nullptr, nullptr, d1_bp, MSG);
    pull_bf<32,0><<<(N*8 + 255)/256, 256, 0, stream>>>(MSG, off, endo, csr, nullptr, AGG);
    gemm_mfma<32,32,128,true,true><<<GM, 256, 0, stream>>>(AGG, b_d1Wl, zbf, b_d1Wr, d1_bl, R1bf);

    // ---- conv4 (d2): 128 -> 64 = x_rec ----
    gemm_proj3<64><<<GM, 256, 0, stream>>>(R1bf, b_d2Wp, d2_bp, b_d2Wl, b_d2Wr, d2_bl, MSG, xrec);
    pull_bf<64,1><<<(N*16 + 255)/256, 256, 0, stream>>>(MSG, off, endo, csr, xrec, nullptr);
}

// Round 17
// 275.224 us; speedup vs baseline: 1.0689x; 1.0339x over previous
//
#include <hip/hip_runtime.h>

constexpr int N = 100000;
constexpr int E = 1600000;
constexpr int NB = (N + 511) / 512;     // 196 dst-buckets of 512 nodes
constexpr int CAPB = 9216;              // fixed bucket capacity (mean 8168, +11 sigma)

using bf16x8 = __attribute__((ext_vector_type(8))) short;
using f32x4  = __attribute__((ext_vector_type(4))) float;

__device__ inline unsigned short f2bf(float x) {
    unsigned int b = __builtin_bit_cast(unsigned int, x);
    b = (b + 0x7FFFu + ((b >> 16) & 1u)) >> 16;
    return (unsigned short)b;
}
__device__ inline float bf2f(unsigned int u) {
    unsigned int b = u << 16;
    return __builtin_bit_cast(float, b);
}

// ================= unified fp32->bf16 prep (weights + x) + bcur init =================
struct WC13 {
    const float* s[13];
    unsigned short* d[13];
    int n8[13];     // element count / 8
};
__global__ __launch_bounds__(256) void conv_all(WC13 wc, int* __restrict__ bcur) {
    const int mi = blockIdx.y;
    if (mi == 0 && blockIdx.x == 0 && threadIdx.x < NB)
        bcur[threadIdx.x] = threadIdx.x * CAPB;   // binit folded
    const float* s = wc.s[mi];
    unsigned short* d = wc.d[mi];
    const int n8 = wc.n8[mi];
    for (int i = blockIdx.x * 256 + threadIdx.x; i < n8; i += gridDim.x * 256) {
        const float* p = s + (size_t)i * 8;
        float4 v0 = *(const float4*)p;
        float4 v1 = *(const float4*)(p + 4);
        uint4 o;
        o.x = (unsigned)f2bf(v0.x) | ((unsigned)f2bf(v0.y) << 16);
        o.y = (unsigned)f2bf(v0.z) | ((unsigned)f2bf(v0.w) << 16);
        o.z = (unsigned)f2bf(v1.x) | ((unsigned)f2bf(v1.y) << 16);
        o.w = (unsigned)f2bf(v1.z) | ((unsigned)f2bf(v1.w) << 16);
        *(uint4*)(d + (size_t)i * 8) = o;
    }
}

// ================= bucketed CSR build (fixed-capacity, R13/R14-verified) =================
__global__ __launch_bounds__(1024) void bucket_scatter(const int* __restrict__ ei,
                                                       int* __restrict__ bcur,
                                                       int* __restrict__ pairs) {
    __shared__ int lh[NB], lbase[NB], lcur[NB];
    const int per = (E + gridDim.x - 1) / gridDim.x;
    const int beg = blockIdx.x * per;
    const int end = min(E, beg + per);
    for (int i = threadIdx.x; i < NB; i += 1024) { lh[i] = 0; lcur[i] = 0; }
    __syncthreads();
    for (int e = beg + threadIdx.x; e < end; e += 1024)
        atomicAdd(&lh[ei[E + e] >> 9], 1);
    __syncthreads();
    for (int i = threadIdx.x; i < NB; i += 1024)
        lbase[i] = lh[i] ? atomicAdd(&bcur[i], lh[i]) : 0;
    __syncthreads();
    for (int e = beg + threadIdx.x; e < end; e += 1024) {
        int s = ei[e], d = ei[E + e];
        int b = d >> 9;
        int r = atomicAdd(&lcur[b], 1);
        int p = lbase[b] + r;
        if (p < (b + 1) * CAPB) pairs[p] = (s << 9) | (d & 511);  // overflow guard
    }
}

__global__ __launch_bounds__(256) void bucket_csr(const int* __restrict__ pairs,
                                                  const int* __restrict__ bcur,
                                                  int* __restrict__ csr,
                                                  int* __restrict__ off,
                                                  int* __restrict__ endo) {
    __shared__ int lcsr[CAPB];
    __shared__ int lh[512], lo[512], lc[512], st[256];
    const int b = blockIdx.x;
    const int base = b * CAPB;
    int cnt = bcur[b] - base;
    if (cnt > CAPB) cnt = CAPB;
    const int t = threadIdx.x;
    lh[t] = 0; lh[t + 256] = 0;
    __syncthreads();
    for (int i = t; i < cnt; i += 256)
        atomicAdd(&lh[pairs[base + i] & 511], 1);
    __syncthreads();
    int a0 = lh[2 * t], a1 = lh[2 * t + 1];
    int ps = a0 + a1;
    st[t] = ps;
    __syncthreads();
    for (int d = 1; d < 256; d <<= 1) {
        int u = (t >= d) ? st[t - d] : 0;
        __syncthreads();
        st[t] += u;
        __syncthreads();
    }
    int excl = st[t] - ps;
    lo[2 * t] = excl;      lo[2 * t + 1] = excl + a0;
    lc[2 * t] = excl;      lc[2 * t + 1] = excl + a0;
    __syncthreads();
    {
        int node0 = b * 512 + 2 * t;
        if (node0 < N)     { off[node0] = base + excl;          endo[node0] = base + excl + a0; }
        int node1 = node0 + 1;
        if (node1 < N)     { off[node1] = base + excl + a0;     endo[node1] = base + excl + a0 + a1; }
    }
    for (int i = t; i < cnt; i += 256) {
        int v = pairs[base + i];
        int pos = atomicAdd(&lc[v & 511], 1);
        if (pos < CAPB) lcsr[pos] = v >> 9;
    }
    __syncthreads();
    for (int i = t; i < cnt; i += 256) csr[base + i] = lcsr[i];
}

// ================= pull aggregation over bf16 messages (R14/R16-verified) =================
// MODE 0: write bf16 agg only. MODE 1: fp32 add into outf. MODE 2: both.
template<int C, int MODE>
__global__ __launch_bounds__(256) void pull_bf(const unsigned short* __restrict__ feat,
                                               const int* __restrict__ off,
                                               const int* __restrict__ endo,
                                               const int* __restrict__ csr,
                                               float* __restrict__ outf,
                                               unsigned short* __restrict__ outb) {
    constexpr int TPN = C / 8;          // threads per node per sub-group
    int t = blockIdx.x * 256 + threadIdx.x;
    int n = t / (2 * TPN);
    int r = t % (2 * TPN);
    int sub = r / TPN;
    int g = r % TPN;
    if (n >= N) return;
    int beg = off[n];
    int end = endo[n];
    int cnt = end - beg;
    int mid = beg + ((cnt + 1) >> 1);
    int j    = sub ? mid : beg;
    int jend = sub ? end : mid;

    float a[8];
    #pragma unroll
    for (int i = 0; i < 8; ++i) a[i] = 0.f;

    for (; j + 4 <= jend; j += 4) {
        int s0 = csr[j], s1 = csr[j + 1], s2 = csr[j + 2], s3 = csr[j + 3];
        uint4 v0 = *(const uint4*)(feat + (size_t)s0 * C + g * 8);
        uint4 v1 = *(const uint4*)(feat + (size_t)s1 * C + g * 8);
        uint4 v2 = *(const uint4*)(feat + (size_t)s2 * C + g * 8);
        uint4 v3 = *(const uint4*)(feat + (size_t)s3 * C + g * 8);
        a[0] += bf2f(v0.x & 0xFFFFu) + bf2f(v1.x & 0xFFFFu) + bf2f(v2.x & 0xFFFFu) + bf2f(v3.x & 0xFFFFu);
        a[1] += bf2f(v0.x >> 16)     + bf2f(v1.x >> 16)     + bf2f(v2.x >> 16)     + bf2f(v3.x >> 16);
        a[2] += bf2f(v0.y & 0xFFFFu) + bf2f(v1.y & 0xFFFFu) + bf2f(v2.y & 0xFFFFu) + bf2f(v3.y & 0xFFFFu);
        a[3] += bf2f(v0.y >> 16)     + bf2f(v1.y >> 16)     + bf2f(v2.y >> 16)     + bf2f(v3.y >> 16);
        a[4] += bf2f(v0.z & 0xFFFFu) + bf2f(v1.z & 0xFFFFu) + bf2f(v2.z & 0xFFFFu) + bf2f(v3.z & 0xFFFFu);
        a[5] += bf2f(v0.z >> 16)     + bf2f(v1.z >> 16)     + bf2f(v2.z >> 16)     + bf2f(v3.z >> 16);
        a[6] += bf2f(v0.w & 0xFFFFu) + bf2f(v1.w & 0xFFFFu) + bf2f(v2.w & 0xFFFFu) + bf2f(v3.w & 0xFFFFu);
        a[7] += bf2f(v0.w >> 16)     + bf2f(v1.w >> 16)     + bf2f(v2.w >> 16)     + bf2f(v3.w >> 16);
    }
    for (; j < jend; ++j) {
        int s = csr[j];
        uint4 v = *(const uint4*)(feat + (size_t)s * C + g * 8);
        a[0] += bf2f(v.x & 0xFFFFu); a[1] += bf2f(v.x >> 16);
        a[2] += bf2f(v.y & 0xFFFFu); a[3] += bf2f(v.y >> 16);
        a[4] += bf2f(v.z & 0xFFFFu); a[5] += bf2f(v.z >> 16);
        a[6] += bf2f(v.w & 0xFFFFu); a[7] += bf2f(v.w >> 16);
    }
    // merge the two halves (partner lane differs by TPN; same node, same g)
    #pragma unroll
    for (int i = 0; i < 8; ++i) a[i] += __shfl_xor(a[i], TPN);
    if (sub) return;

    if (MODE >= 1) {
        float* op = outf + (size_t)n * C + g * 8;
        float4 b0 = *(const float4*)op, b1 = *(const float4*)(op + 4);
        a[0] += b0.x; a[1] += b0.y; a[2] += b0.z; a[3] += b0.w;
        a[4] += b1.x; a[5] += b1.y; a[6] += b1.z; a[7] += b1.w;
        *(float4*)op       = make_float4(a[0], a[1], a[2], a[3]);
        *(float4*)(op + 4) = make_float4(a[4], a[5], a[6], a[7]);
    }
    if (MODE != 1) {
        uint4 o;
        o.x = (unsigned)f2bf(a[0]) | ((unsigned)f2bf(a[1]) << 16);
        o.y = (unsigned)f2bf(a[2]) | ((unsigned)f2bf(a[3]) << 16);
        o.z = (unsigned)f2bf(a[4]) | ((unsigned)f2bf(a[5]) << 16);
        o.w = (unsigned)f2bf(a[6]) | ((unsigned)f2bf(a[7]) << 16);
        *(uint4*)(outb + (size_t)n * C + g * 8) = o;
    }
}

// ================= MFMA bf16 GEMM, 128-row blocks (R17) =================
// 512 threads = 8 waves; wave w owns rows w*16..+15 of a 128-row tile.
// Halves per-element B-staging vs 64-row blocks; KV=128 LDS 69.6KB ->
// 2 blocks/CU = 16 waves/CU (up from 12). Fragments m89/m97-verified.
template<int K1, int K2, int M, bool RELU, bool OBF>
__global__ __launch_bounds__(512) void gemm_mfma(
    const unsigned short* __restrict__ in1, const unsigned short* __restrict__ W1,
    const unsigned short* __restrict__ in2, const unsigned short* __restrict__ W2,
    const float* __restrict__ bias, void* __restrict__ outv)
{
    constexpr int KV = K1 + K2;
    constexpr int SK = KV + 8;
    constexpr int NF = M / 16;
    __shared__ unsigned short As[128 * SK];
    __shared__ unsigned short Bs[M * SK];

    const int tid = threadIdx.x;
    const int row0 = blockIdx.x * 128;

    constexpr int AV = 128 * (KV / 8);
    for (int idx = tid; idx < AV; idx += 512) {
        int r = idx / (KV / 8), c = (idx % (KV / 8)) * 8;
        int rr = row0 + r;
        uint4 v = {0u, 0u, 0u, 0u};
        if (rr < N) {
            if constexpr (K2 == 0) {
                v = *(const uint4*)(in1 + (size_t)rr * K1 + c);
            } else {
                v = (c < K1) ? *(const uint4*)(in1 + (size_t)rr * K1 + c)
                             : *(const uint4*)(in2 + (size_t)rr * K2 + (c - K1));
            }
        }
        *(uint4*)&As[r * SK + c] = v;
    }
    constexpr int BV = M * (KV / 8);
    for (int idx = tid; idx < BV; idx += 512) {
        int m = idx / (KV / 8), c = (idx % (KV / 8)) * 8;
        uint4 v;
        if constexpr (K2 == 0) {
            v = *(const uint4*)(W1 + (size_t)m * K1 + c);
        } else {
            v = (c < K1) ? *(const uint4*)(W1 + (size_t)m * K1 + c)
                         : *(const uint4*)(W2 + (size_t)m * K2 + (c - K1));
        }
        *(uint4*)&Bs[m * SK + c] = v;
    }
    __syncthreads();

    const int lane = tid & 63;
    const int wv   = tid >> 6;        // 0..7 -> row group of 16
    const int lrow = lane & 15;
    const int kg   = lane >> 4;

    f32x4 acc[NF];
    #pragma unroll
    for (int cf = 0; cf < NF; ++cf) acc[cf] = (f32x4){0.f, 0.f, 0.f, 0.f};

    #pragma unroll
    for (int k0 = 0; k0 < KV; k0 += 32) {
        bf16x8 a = *(const bf16x8*)&As[(wv * 16 + lrow) * SK + k0 + kg * 8];
        #pragma unroll
        for (int cf = 0; cf < NF; ++cf) {
            bf16x8 b = *(const bf16x8*)&Bs[(cf * 16 + lrow) * SK + k0 + kg * 8];
            acc[cf] = __builtin_amdgcn_mfma_f32_16x16x32_bf16(a, b, acc[cf], 0, 0, 0);
        }
    }

    #pragma unroll
    for (int cf = 0; cf < NF; ++cf) {
        int col = cf * 16 + lrow;
        float bsv = bias ? bias[col] : 0.f;
        #pragma unroll
        for (int r = 0; r < 4; ++r) {
            int row = row0 + wv * 16 + kg * 4 + r;
            if (row < N) {
                float v = acc[cf][r] + bsv;
                if (RELU) v = fmaxf(v, 0.f);
                if constexpr (OBF)
                    ((unsigned short*)outv)[(size_t)row * M + col] = f2bf(v);
                else
                    ((float*)outv)[(size_t)row * M + col] = v;
            }
        }
    }
}

// ================= fused proj+msg+root GEMM (conv2/conv4 head, R11-verified) =================
template<int M2>
__global__ __launch_bounds__(256) void gemm_proj3(
    const unsigned short* __restrict__ in, const unsigned short* __restrict__ Wp,
    const float* __restrict__ bp,
    const unsigned short* __restrict__ Wl, const unsigned short* __restrict__ Wr,
    const float* __restrict__ bl,
    unsigned short* __restrict__ msg, float* __restrict__ zout)
{
    constexpr int K = 128, SK = K + 8, NF = 8, NF2 = M2 / 16;
    __shared__ unsigned short As[64 * SK];
    __shared__ unsigned short Bs[128 * SK];
    __shared__ unsigned short Hs[64 * SK];
    const int tid = threadIdx.x;
    const int row0 = blockIdx.x * 64;

    for (int idx = tid; idx < 64 * 16; idx += 256) {
        int r = idx >> 4, c = (idx & 15) * 8;
        int n = row0 + r;
        uint4 v = {0u, 0u, 0u, 0u};
        if (n < N) v = *(const uint4*)(in + (size_t)n * K + c);
        *(uint4*)&As[r * SK + c] = v;
    }
    for (int idx = tid; idx < 128 * 16; idx += 256) {
        int m = idx >> 4, c = (idx & 15) * 8;
        *(uint4*)&Bs[m * SK + c] = *(const uint4*)(Wp + (size_t)m * K + c);
    }
    __syncthreads();

    const int lane = tid & 63;
    const int wv = tid >> 6, lrow = lane & 15, kg = lane >> 4;

    f32x4 acc[NF];
    #pragma unroll
    for (int cf = 0; cf < NF; ++cf) acc[cf] = (f32x4){0.f, 0.f, 0.f, 0.f};
    #pragma unroll
    for (int k0 = 0; k0 < K; k0 += 32) {
        bf16x8 a = *(const bf16x8*)&As[(wv * 16 + lrow) * SK + k0 + kg * 8];
        #pragma unroll
        for (int cf = 0; cf < NF; ++cf) {
            bf16x8 b = *(const bf16x8*)&Bs[(cf * 16 + lrow) * SK + k0 + kg * 8];
            acc[cf] = __builtin_amdgcn_mfma_f32_16x16x32_bf16(a, b, acc[cf], 0, 0, 0);
        }
    }
    #pragma unroll
    for (int cf = 0; cf < NF; ++cf) {
        int col = cf * 16 + lrow;
        float bv = bp[col];
        #pragma unroll
        for (int r = 0; r < 4; ++r)
            Hs[(wv * 16 + kg * 4 + r) * SK + col] = f2bf(fmaxf(acc[cf][r] + bv, 0.f));
    }
    __syncthreads();
    for (int idx = tid; idx < 2 * M2 * 16; idx += 256) {
        int m = idx >> 4, c = (idx & 15) * 8;
        uint4 v = (m < M2) ? *(const uint4*)(Wl + (size_t)m * K + c)
                           : *(const uint4*)(Wr + (size_t)(m - M2) * K + c);
        *(uint4*)&Bs[m * SK + c] = v;
    }
    __syncthreads();

    f32x4 am[NF2], az[NF2];
    #pragma unroll
    for (int cf = 0; cf < NF2; ++cf) {
        am[cf] = (f32x4){0.f, 0.f, 0.f, 0.f};
        az[cf] = (f32x4){0.f, 0.f, 0.f, 0.f};
    }
    #pragma unroll
    for (int k0 = 0; k0 < K; k0 += 32) {
        bf16x8 aH = *(const bf16x8*)&Hs[(wv * 16 + lrow) * SK + k0 + kg * 8];
        bf16x8 aR = *(const bf16x8*)&As[(wv * 16 + lrow) * SK + k0 + kg * 8];
        #pragma unroll
        for (int cf = 0; cf < NF2; ++cf) {
            bf16x8 b1 = *(const bf16x8*)&Bs[(cf * 16 + lrow) * SK + k0 + kg * 8];
            bf16x8 b2 = *(const bf16x8*)&Bs[(M2 + cf * 16 + lrow) * SK + k0 + kg * 8];
            am[cf] = __builtin_amdgcn_mfma_f32_16x16x32_bf16(aH, b1, am[cf], 0, 0, 0);
            az[cf] = __builtin_amdgcn_mfma_f32_16x16x32_bf16(aR, b2, az[cf], 0, 0, 0);
        }
    }
    #pragma unroll
    for (int cf = 0; cf < NF2; ++cf) {
        int col = cf * 16 + lrow;
        float blv = bl[col];
        #pragma unroll
        for (int r = 0; r < 4; ++r) {
            int row = row0 + wv * 16 + kg * 4 + r;
            if (row < N) {
                msg[(size_t)row * M2 + col]  = f2bf(am[cf][r]);
                zout[(size_t)row * M2 + col] = az[cf][r] + blv;
            }
        }
    }
}

extern "C" void kernel_launch(void* const* d_in, const int* in_sizes, int n_in,
                              void* d_out, int out_size, void* d_ws, size_t ws_size,
                              hipStream_t stream)
{
    const float* x   = (const float*)d_in[0];
    const int*   ei  = (const int*)d_in[1];
    const float *e1_Wp=(const float*)d_in[2],  *e1_bp=(const float*)d_in[3],
                *e1_Wl=(const float*)d_in[4],  *e1_bl=(const float*)d_in[5],
                *e1_Wr=(const float*)d_in[6];
    const float *e2_Wp=(const float*)d_in[7],  *e2_bp=(const float*)d_in[8],
                *e2_Wl=(const float*)d_in[9],  *e2_bl=(const float*)d_in[10],
                *e2_Wr=(const float*)d_in[11];
    const float *d1_Wp=(const float*)d_in[12], *d1_bp=(const float*)d_in[13],
                *d1_Wl=(const float*)d_in[14], *d1_bl=(const float*)d_in[15],
                *d1_Wr=(const float*)d_in[16];
    const float *d2_Wp=(const float*)d_in[17], *d2_bp=(const float*)d_in[18],
                *d2_Wl=(const float*)d_in[19], *d2_bl=(const float*)d_in[20],
                *d2_Wr=(const float*)d_in[21];

    typedef unsigned short u16;

    // ---- workspace ----
    int* off  = (int*)d_ws;                       // N
    int* endo = off + N;                          // N
    int* csr  = endo + N;                         // NB*CAPB (bucket-strided)
    u16* xbf  = (u16*)(csr + NB * CAPB);          // [N][64]
    u16* R1bf = xbf  + (size_t)N * 64;            // [N][128]
    u16* MSG  = R1bf + (size_t)N * 128;           // [N][64] msgs
    u16* AGG  = MSG  + (size_t)N * 64;            // [N][64] aggregates
    u16* zbf  = AGG  + (size_t)N * 64;            // [N][32]
    u16* WB   = zbf  + (size_t)N * 32;            // bf16 weights
    int* bcur = (int*)(WB + 87040);               // NB
    int* pairs = (int*)MSG;   // NB*CAPB ints; CSR build precedes MSG use

    u16* b_e1Wp = WB;
    u16* b_e1Wl = b_e1Wp + 4096;
    u16* b_e1Wr = b_e1Wl + 8192;
    u16* b_e2Wr = b_e1Wr + 8192;
    u16* b_e2Wp = b_e2Wr + 4096;
    u16* b_e2Wl = b_e2Wp + 16384;
    u16* b_d1Wp = b_e2Wl + 4096;
    u16* b_d1Wl = b_d1Wp + 1024;
    u16* b_d1Wr = b_d1Wl + 4096;
    u16* b_d2Wr = b_d1Wr + 4096;
    u16* b_d2Wp = b_d2Wr + 8192;
    u16* b_d2Wl = b_d2Wp + 16384;

    float* xrec = (float*)d_out;                  // [N][64]
    float* z    = xrec + (size_t)N * 64;          // [N][32]

    const int GM  = (N + 63) / 64;                // 1563 (proj3 grid)
    const int GM2 = (N + 127) / 128;              // 782 (gemm_mfma grid)

    // ---- unified prep: 12 weight converts + x convert + bcur init ----
    WC13 wc;
    const float* ws_[13] = {e1_Wp, e1_Wl, e1_Wr, e2_Wr, e2_Wp, e2_Wl,
                            d1_Wp, d1_Wl, d1_Wr, d2_Wr, d2_Wp, d2_Wl, x};
    u16* wd_[13] = {b_e1Wp, b_e1Wl, b_e1Wr, b_e2Wr, b_e2Wp, b_e2Wl,
                    b_d1Wp, b_d1Wl, b_d1Wr, b_d2Wr, b_d2Wp, b_d2Wl, xbf};
    int wn_[13] = {512, 1024, 1024, 512, 2048, 512,
                   128, 512, 512, 1024, 2048, 1024, N * 8};
    for (int i = 0; i < 13; ++i) { wc.s[i] = ws_[i]; wc.d[i] = wd_[i]; wc.n8[i] = wn_[i]; }
    conv_all<<<dim3(128, 13), 256, 0, stream>>>(wc, bcur);

    // ---- bucketed CSR build ----
    bucket_scatter<<<256, 1024, 0, stream>>>(ei, bcur, pairs);
    bucket_csr<<<NB, 256, 0, stream>>>(pairs, bcur, csr, off, endo);

    // ---- conv1 (e1): 64 -> 128, relu ----
    gemm_mfma<64,0,64,true,true><<<GM2, 512, 0, stream>>>(xbf, b_e1Wp, nullptr, nullptr, e1_bp, MSG);
    pull_bf<64,0><<<(N*16 + 255)/256, 256, 0, stream>>>(MSG, off, endo, csr, nullptr, AGG);
    gemm_mfma<64,64,128,true,true><<<GM2, 512, 0, stream>>>(AGG, b_e1Wl, xbf, b_e1Wr, e1_bl, R1bf);

    // ---- conv2 (e2): 128 -> 32 = z ----
    gemm_proj3<32><<<GM, 256, 0, stream>>>(R1bf, b_e2Wp, e2_bp, b_e2Wl, b_e2Wr, e2_bl, MSG, z);
    pull_bf<32,2><<<(N*8 + 255)/256, 256, 0, stream>>>(MSG, off, endo, csr, z, zbf);

    // ---- conv3 (d1): 32 -> 128, relu ----
    gemm_mfma<32,0,32,true,true><<<GM2, 512, 0, stream>>>(zbf, b_d1Wp, nullptr, nullptr, d1_bp, MSG);
    pull_bf<32,0><<<(N*8 + 255)/256, 256, 0, stream>>>(MSG, off, endo, csr, nullptr, AGG);
    gemm_mfma<32,32,128,true,true><<<GM2, 512, 0, stream>>>(AGG, b_d1Wl, zbf, b_d1Wr, d1_bl, R1bf);

    // ---- conv4 (d2): 128 -> 64 = x_rec ----
    gemm_proj3<64><<<GM, 256, 0, stream>>>(R1bf, b_d2Wp, d2_bp, b_d2Wl, b_d2Wr, d2_bl, MSG, xrec);
    pull_bf<64,1><<<(N*16 + 255)/256, 256, 0, stream>>>(MSG, off, endo, csr, xrec, nullptr);
}